// Round 2
// baseline (868.186 us; speedup 1.0000x reference)
//
#include <hip/hip_runtime.h>
#include <stdint.h>

#define LSEQ 32768
#define NCH 256      // scan chunks
#define TCH 128      // timesteps per chunk  (NCH*TCH == LSEQ)

typedef _Float16 half8 __attribute__((ext_vector_type(8)));
typedef _Float16 half4v __attribute__((ext_vector_type(4)));
typedef float f32x4 __attribute__((ext_vector_type(4)));

__device__ __forceinline__ float sigmoidf_(float x) { return 1.f / (1.f + __expf(-x)); }
__device__ __forceinline__ float gelu_(float x) {
    float z = 0.7978845608028654f * (x + 0.044715f * x * x * x);
    float e = __expf(2.f * z);
    float t = 1.f - 2.f / (e + 1.f);   // tanh(z)
    return 0.5f * x * (1.f + t);
}

// async global->LDS, 16B per lane; LDS dest = wave-uniform base + lane*16
__device__ __forceinline__ void gll16(const _Float16* g, _Float16* l) {
    __builtin_amdgcn_global_load_lds((__attribute__((address_space(1))) void*)g,
                                     (__attribute__((address_space(3))) void*)l, 16, 0, 0);
}

// ---------------------------------------------------------------------------
// fp16 MFMA GEMM core: C(BMxBN) = A(M x 256) @ Wt(N x 256)^T
// LDS fragment-major chunks (64 lanes x 16B), staged via global_load_lds.
// MFMA 16x16x32_f16: Aop[m=lane&15][k=quad*8+j], D[row=quad*4+r][col=lane&15].
// SPLIT=true (GLU): wave wn covers cols wn*64..+63 (nt 0..3) AND 256+wn*64.. (nt 4..7).
// ---------------------------------------------------------------------------
template <int BM, int BN, int WR, int WC, bool SPLIT = false>
__device__ __forceinline__ void gemm_core(const _Float16* __restrict__ A,
                                          const _Float16* __restrict__ Wt,
                                          _Float16* sA, _Float16* sW,
                                          int m0, int n0,
                                          f32x4 (&acc)[BM / (WR * 16)][BN / (WC * 16)]) {
    constexpr int MT = BM / (WR * 16);
    constexpr int NT = BN / (WC * 16);
    constexpr int CA = 2 * (BM / 16);
    constexpr int CW = 2 * (BN / 16);
    const int tid = threadIdx.x;
    const int wv = tid >> 6;
    const int lane = tid & 63;
    const int wm = wv / WC;
    const int wn = wv % WC;

    f32x4 zero = {0.f, 0.f, 0.f, 0.f};
#pragma unroll
    for (int i = 0; i < MT; ++i)
#pragma unroll
        for (int j = 0; j < NT; ++j) acc[i][j] = zero;

    for (int kb = 0; kb < 256; kb += 64) {
        __syncthreads();
#pragma unroll
        for (int i = 0; i < CA / 4; ++i) {
            int c = i * 4 + wv;
            int ks = c / (BM / 16), r16 = c % (BM / 16);
            const _Float16* gp = A + (size_t)(m0 + r16 * 16 + (lane & 15)) * 256 + kb + ks * 32 + (lane >> 4) * 8;
            gll16(gp, sA + c * 512);
        }
#pragma unroll
        for (int i = 0; i < CW / 4; ++i) {
            int c = i * 4 + wv;
            int ks = c / (BN / 16), n16 = c % (BN / 16);
            const _Float16* gp = Wt + (size_t)(n0 + n16 * 16 + (lane & 15)) * 256 + kb + ks * 32 + (lane >> 4) * 8;
            gll16(gp, sW + c * 512);
        }
        __syncthreads();
#pragma unroll
        for (int ks = 0; ks < 2; ++ks) {
            half8 af[MT], bf[NT];
#pragma unroll
            for (int mt = 0; mt < MT; ++mt)
                af[mt] = *(const half8*)(sA + (ks * (BM / 16) + wm * MT + mt) * 512 + lane * 8);
#pragma unroll
            for (int nt = 0; nt < NT; ++nt) {
                int n16 = SPLIT ? ((nt < NT / 2 ? 0 : BN / 32) + wn * (NT / 2) + (nt % (NT / 2)))
                                : (wn * NT + nt);
                bf[nt] = *(const half8*)(sW + (ks * (BN / 16) + n16) * 512 + lane * 8);
            }
#pragma unroll
            for (int mt = 0; mt < MT; ++mt)
#pragma unroll
                for (int nt = 0; nt < NT; ++nt)
                    acc[mt][nt] = __builtin_amdgcn_mfma_f32_16x16x32_f16(af[mt], bf[nt], acc[mt][nt], 0, 0, 0);
        }
    }
    __syncthreads();
}

// --------------------------- setup kernels ---------------------------------
__global__ __launch_bounds__(512) void s5_k0a(const float* __restrict__ lre, const float* __restrict__ lim,
                                              const float* __restrict__ lstep,
                                              float* aR, float* aI, float* cbR, float* cbI,
                                              float* aTR, float* aTI, float* alp, float* ralp) {
    int i = threadIdx.x;
    float st = expf(lstep[i]);
    float lr = lre[i] * st, li = lim[i] * st;
    float ea = expf(lr);
    float ar = ea * cosf(li), ai = ea * sinf(li);
    float den = lre[i] * lre[i] + lim[i] * lim[i];
    float nr = ar - 1.f, ni = ai;
    float cr = (nr * lre[i] + ni * lim[i]) / den;
    float ci = (ni * lre[i] - nr * lim[i]) / den;
    float cm = sqrtf(cr * cr + ci * ci);
    float al = sqrtf(2.83f / fmaxf(cm, 1e-8f));
    float eT = expf(lr * (float)TCH);
    aR[i] = ar; aI[i] = ai;
    cbR[i] = cr; cbI[i] = ci;
    aTR[i] = eT * cosf(li * (float)TCH);
    aTI[i] = eT * sinf(li * (float)TCH);
    alp[i] = al; ralp[i] = 1.f / al;
}

__global__ __launch_bounds__(256) void s5_k0b(const float* __restrict__ Bre, const float* __restrict__ Bim,
                                              const float* __restrict__ Cre, const float* __restrict__ Cim,
                                              const float* __restrict__ W1, const float* __restrict__ W2,
                                              const float* __restrict__ b1, const float* __restrict__ b2,
                                              const float* __restrict__ Wout,
                                              const float* __restrict__ cbR, const float* __restrict__ cbI,
                                              const float* __restrict__ alp, const float* __restrict__ ralp,
                                              _Float16* Wbu, _Float16* Wc, _Float16* Wglu,
                                              _Float16* WoutT, float* bglu) {
    int stride = gridDim.x * blockDim.x;
    int tid0 = blockIdx.x * blockDim.x + threadIdx.x;
    for (int i = tid0; i < 262144; i += stride) {
        int l = i >> 16, n = (i >> 8) & 255, k = i & 255;
        float v;
        if (n < 128) {
            int p = l * 128 + n;
            v = (cbR[p] * Bre[p * 256 + k] - cbI[p] * Bim[p * 256 + k]) * alp[p];
        } else {
            int p = l * 128 + n - 128;
            v = (cbR[p] * Bim[p * 256 + k] + cbI[p] * Bre[p * 256 + k]) * alp[p];
        }
        Wbu[i] = (_Float16)v;
    }
    for (int i = tid0; i < 262144; i += stride) {
        int l = i >> 16, n = (i >> 8) & 255, k = i & 255;
        float base = (k < 128) ? 2.f * Cre[(l * 256 + n) * 128 + k]
                               : -2.f * Cim[(l * 256 + n) * 128 + (k - 128)];
        Wc[i] = (_Float16)(base * ralp[l * 128 + (k & 127)]);
    }
    // Wglu deinterleaved: n<256 -> W1 col n ; n>=256 -> W2 col n-256
    for (int i = tid0; i < 524288; i += stride) {
        int l = i >> 17, n = (i >> 8) & 511, k = i & 255;
        int j = (n < 256) ? n : n - 256;
        const float* src = (n < 256) ? W1 : W2;
        Wglu[i] = (_Float16)src[(l * 256 + k) * 256 + j];
    }
    for (int i = tid0; i < 16384; i += stride) {
        int n = i >> 8, k = i & 255;
        WoutT[i] = (_Float16)Wout[k * 64 + n];
    }
    for (int i = tid0; i < 2048; i += stride) {
        int l = i >> 9, n = i & 511;
        bglu[i] = (n < 256) ? b1[l * 256 + n] : b2[l * 256 + (n - 256)];
    }
}

// latent expand + leaky_relu + layer-0 LN row (all in fp32)
__global__ __launch_bounds__(256) void s5_k0c(const float* __restrict__ latent, const float* __restrict__ W,
                                              const float* __restrict__ b,
                                              const float* __restrict__ gamma, const float* __restrict__ beta,
                                              float* __restrict__ x0, float* __restrict__ hrow,
                                              _Float16* __restrict__ hrow16) {
    __shared__ float lat[256];
    __shared__ float r1[4], r2[4];
    int tid = threadIdx.x;
    lat[tid] = latent[tid];
    __syncthreads();
    float s = b[tid];
    for (int k = 0; k < 256; ++k) s += lat[k] * W[k * 256 + tid];
    s = (s > 0.f) ? s : 0.01f * s;
    x0[tid] = s;
    float a = s, q = s * s;
#pragma unroll
    for (int off = 1; off < 64; off <<= 1) { a += __shfl_xor(a, off, 64); q += __shfl_xor(q, off, 64); }
    if ((tid & 63) == 0) { r1[tid >> 6] = a; r2[tid >> 6] = q; }
    __syncthreads();
    float S1 = r1[0] + r1[1] + r1[2] + r1[3];
    float S2 = r2[0] + r2[1] + r2[2] + r2[3];
    float mu = S1 * (1.f / 256.f);
    float var = S2 * (1.f / 256.f) - mu * mu;
    float rs = rsqrtf(fmaxf(var, 0.f) + 1e-6f);
    float hv = (s - mu) * rs * gamma[tid] + beta[tid];
    hrow[tid] = hv;
    hrow16[tid] = (_Float16)hv;
}

// layer-0 Bu row (h row is constant): burow[n] = hrow . Wbu[0][n][:]
__global__ __launch_bounds__(128) void s5_k0e(const float* __restrict__ hrow, const _Float16* __restrict__ Wbu,
                                              float* __restrict__ burow) {
    __shared__ float hs[256];
    int tid = threadIdx.x;
    hs[tid] = hrow[tid]; hs[tid + 128] = hrow[tid + 128];
    __syncthreads();
    int n = blockIdx.x * 128 + tid;
    float s = 0.f;
    for (int k = 0; k < 256; ++k) s += hs[k] * (float)Wbu[n * 256 + k];
    burow[n] = s;
}

__global__ __launch_bounds__(256) void s5_k1_fill(const float* __restrict__ x0, float* __restrict__ x) {
    int i = blockIdx.x * 256 + threadIdx.x;
    f32x4 v = *(const f32x4*)(x0 + (i & 63) * 4);
    *(f32x4*)(x + i * 4) = v;
}

// --------------------------- per-layer kernels -----------------------------
__global__ __launch_bounds__(256) void s5_k3_gemm_bu(const _Float16* __restrict__ A,
                                                     const _Float16* __restrict__ Wt,
                                                     _Float16* __restrict__ Bu) {
    __shared__ _Float16 sA[128 * 64], sW[128 * 64];
    f32x4 acc[4][4];
    int m0 = blockIdx.x * 128, n0 = blockIdx.y * 128;
    gemm_core<128, 128, 2, 2>(A, Wt, sA, sW, m0, n0, acc);
    int tid = threadIdx.x, wid = tid >> 6, lane = tid & 63, lm = lane & 15, quad = lane >> 4;
    int wm = wid >> 1, wn = wid & 1;
#pragma unroll
    for (int mt = 0; mt < 4; ++mt)
#pragma unroll
        for (int nt = 0; nt < 4; ++nt) {
            int col = n0 + wn * 64 + nt * 16 + lm;
#pragma unroll
            for (int r = 0; r < 4; ++r) {
                int row = m0 + wm * 64 + mt * 16 + quad * 4 + r;
                Bu[row * 256 + col] = (_Float16)acc[mt][nt][r];
            }
        }
}

__global__ __launch_bounds__(128) void s5_k4_scan(const _Float16* __restrict__ Bu,
                                                  const float* __restrict__ burow, int bcast,
                                                  const float* __restrict__ aR, const float* __restrict__ aI,
                                                  _Float16* __restrict__ xsh,
                                                  float* __restrict__ carR, float* __restrict__ carI) {
    int p = threadIdx.x, c = blockIdx.x;
    float ar = aR[p], ai = aI[p];
    float cbr = 0.f, cbi = 0.f;
    if (bcast) { cbr = burow[p]; cbi = burow[p + 128]; }
    float sr = 0.f, si = 0.f;
    int t0 = c * TCH;
#pragma unroll 4
    for (int j = 0; j < TCH; ++j) {
        int t = t0 + j;
        float br = bcast ? cbr : (float)Bu[t * 256 + p];
        float bi = bcast ? cbi : (float)Bu[t * 256 + 128 + p];
        float nr = fmaf(ar, sr, fmaf(-ai, si, br));
        float ni = fmaf(ar, si, fmaf(ai, sr, bi));
        sr = nr; si = ni;
        xsh[t * 256 + p] = (_Float16)sr;
        xsh[t * 256 + p + 128] = (_Float16)si;
    }
    carR[c * 128 + p] = sr;
    carI[c * 128 + p] = si;
}

__global__ __launch_bounds__(128) void s5_k5_carry(const float* __restrict__ carR, const float* __restrict__ carI,
                                                   const float* __restrict__ aTR, const float* __restrict__ aTI,
                                                   float* __restrict__ cinR, float* __restrict__ cinI) {
    int p = threadIdx.x;
    float ar = aTR[p], ai = aTI[p];
    float rr = 0.f, ri = 0.f;
#pragma unroll 8
    for (int c = 0; c < NCH; ++c) {
        cinR[c * 128 + p] = rr;
        cinI[c * 128 + p] = ri;
        float cr = carR[c * 128 + p], ci = carI[c * 128 + p];
        float nr = fmaf(ar, rr, fmaf(-ai, ri, cr));
        float ni = fmaf(ar, ri, fmaf(ai, rr, ci));
        rr = nr; ri = ni;
    }
}

__global__ __launch_bounds__(128) void s5_k6_apply(const _Float16* __restrict__ xsh,
                                                   const float* __restrict__ cinR, const float* __restrict__ cinI,
                                                   const float* __restrict__ aR, const float* __restrict__ aI,
                                                   _Float16* __restrict__ xs2) {
    int p = threadIdx.x, c = blockIdx.x;
    float ar = aR[p], ai = aI[p];
    float cr = cinR[c * 128 + p], ci = cinI[c * 128 + p];
    float fr = ar, fi = ai;
    int t0 = c * TCH;
#pragma unroll 4
    for (int j = 0; j < TCH; ++j) {
        int t = t0 + j;
        float xr = (float)xsh[t * 256 + p] + fr * cr - fi * ci;
        float xi = (float)xsh[t * 256 + p + 128] + fr * ci + fi * cr;
        xs2[t * 256 + p] = (_Float16)xr;
        xs2[t * 256 + p + 128] = (_Float16)xi;
        float nr = fr * ar - fi * ai, ni = fr * ai + fi * ar;
        fr = nr; fi = ni;
    }
}

// C-GEMM + D-skip + gtrxl LN + gelu
__global__ __launch_bounds__(256) void s5_k7_gemm_c(const _Float16* __restrict__ A,
                                                    const _Float16* __restrict__ Wt,
                                                    const _Float16* __restrict__ h, int hstride,
                                                    const float* __restrict__ Dv,
                                                    const float* __restrict__ gamma,
                                                    const float* __restrict__ beta,
                                                    _Float16* __restrict__ g) {
    __shared__ _Float16 sA[64 * 64], sW[256 * 64];
    __shared__ float red1[64][4], red2[64][4], mu_s[64], rs_s[64];
    f32x4 acc[4][4];
    int m0 = blockIdx.x * 64;
    gemm_core<64, 256, 1, 4>(A, Wt, sA, sW, m0, 0, acc);
    int tid = threadIdx.x, wid = tid >> 6, lane = tid & 63, lm = lane & 15, quad = lane >> 4;
#pragma unroll
    for (int nt = 0; nt < 4; ++nt) {
        int col = wid * 64 + nt * 16 + lm;
        float dv = Dv[col];
#pragma unroll
        for (int mt = 0; mt < 4; ++mt)
#pragma unroll
            for (int r = 0; r < 4; ++r) {
                int row = m0 + mt * 16 + quad * 4 + r;
                acc[mt][nt][r] += (float)h[row * hstride + col] * dv;
            }
    }
    float s1[4][4], s2[4][4];
#pragma unroll
    for (int mt = 0; mt < 4; ++mt)
#pragma unroll
        for (int r = 0; r < 4; ++r) {
            float a = 0.f, b = 0.f;
#pragma unroll
            for (int nt = 0; nt < 4; ++nt) {
                float v = acc[mt][nt][r];
                a += v; b += v * v;
            }
#pragma unroll
            for (int off = 1; off < 16; off <<= 1) {
                a += __shfl_xor(a, off, 64);
                b += __shfl_xor(b, off, 64);
            }
            s1[mt][r] = a; s2[mt][r] = b;
        }
    if (lm == 0) {
#pragma unroll
        for (int mt = 0; mt < 4; ++mt)
#pragma unroll
            for (int r = 0; r < 4; ++r) {
                int row = mt * 16 + quad * 4 + r;
                red1[row][wid] = s1[mt][r];
                red2[row][wid] = s2[mt][r];
            }
    }
    __syncthreads();
    if (tid < 64) {
        float a = red1[tid][0] + red1[tid][1] + red1[tid][2] + red1[tid][3];
        float b = red2[tid][0] + red2[tid][1] + red2[tid][2] + red2[tid][3];
        float mu = a * (1.f / 256.f);
        float var = b * (1.f / 256.f) - mu * mu;
        mu_s[tid] = mu;
        rs_s[tid] = rsqrtf(fmaxf(var, 0.f) + 1e-6f);
    }
    __syncthreads();
#pragma unroll
    for (int nt = 0; nt < 4; ++nt) {
        int col = wid * 64 + nt * 16 + lm;
        float ga = gamma[col], be = beta[col];
#pragma unroll
        for (int mt = 0; mt < 4; ++mt)
#pragma unroll
            for (int r = 0; r < 4; ++r) {
                int rl = mt * 16 + quad * 4 + r;
                float hn = (acc[mt][nt][r] - mu_s[rl]) * rs_s[rl] * ga + be;
                g[(m0 + rl) * 256 + col] = (_Float16)gelu_(hn);
            }
    }
}

// GLU + bias + residual + next-layer LN (or raw fp16 mirror on last layer)
__global__ __launch_bounds__(256) void s5_k8_glu_ln(const _Float16* __restrict__ A,
                                                    const _Float16* __restrict__ Wt,
                                                    const float* __restrict__ bgl,
                                                    float* __restrict__ x, _Float16* __restrict__ h,
                                                    const float* __restrict__ gamma,
                                                    const float* __restrict__ beta,
                                                    int write_x, int do_ln) {
    __shared__ _Float16 sA[8 * 512];    // 8 KB
    __shared__ _Float16 sW[64 * 512];   // 64 KB
    __shared__ float red1[64][4], red2[64][4], mu_s[64], rs_s[64];
    f32x4 acc[4][8];
    int m0 = blockIdx.x * 64;
    gemm_core<64, 512, 1, 4, true>(A, Wt, sA, sW, m0, 0, acc);
    int tid = threadIdx.x, wid = tid >> 6, lane = tid & 63, lm = lane & 15, quad = lane >> 4;
    float xn[4][4][4];
    float s1v[4][4], s2v[4][4];
#pragma unroll
    for (int mt = 0; mt < 4; ++mt)
#pragma unroll
        for (int r = 0; r < 4; ++r) { s1v[mt][r] = 0.f; s2v[mt][r] = 0.f; }
#pragma unroll
    for (int ntp = 0; ntp < 4; ++ntp) {
        int col = wid * 64 + ntp * 16 + lm;
        float b1v = bgl[col], b2v = bgl[256 + col];
#pragma unroll
        for (int mt = 0; mt < 4; ++mt)
#pragma unroll
            for (int r = 0; r < 4; ++r) {
                int row = m0 + mt * 16 + quad * 4 + r;
                float u1 = acc[mt][ntp][r] + b1v;
                float u2 = acc[mt][ntp + 4][r] + b2v;
                float y = u1 * sigmoidf_(u2);
                float v = x[row * 256 + col] + y;
                if (write_x) x[row * 256 + col] = v;
                xn[mt][ntp][r] = v;
                s1v[mt][r] += v;
                s2v[mt][r] += v * v;
            }
    }
#pragma unroll
    for (int mt = 0; mt < 4; ++mt)
#pragma unroll
        for (int r = 0; r < 4; ++r) {
            float a = s1v[mt][r], b = s2v[mt][r];
#pragma unroll
            for (int off = 1; off < 16; off <<= 1) {
                a += __shfl_xor(a, off, 64);
                b += __shfl_xor(b, off, 64);
            }
            if (lm == 0) {
                int rl = mt * 16 + quad * 4 + r;
                red1[rl][wid] = a; red2[rl][wid] = b;
            }
        }
    __syncthreads();
    if (tid < 64) {
        float a = red1[tid][0] + red1[tid][1] + red1[tid][2] + red1[tid][3];
        float b = red2[tid][0] + red2[tid][1] + red2[tid][2] + red2[tid][3];
        float mu = a * (1.f / 256.f);
        float var = b * (1.f / 256.f) - mu * mu;
        mu_s[tid] = mu;
        rs_s[tid] = rsqrtf(fmaxf(var, 0.f) + 1e-6f);
    }
    __syncthreads();
#pragma unroll
    for (int ntp = 0; ntp < 4; ++ntp) {
        int col = wid * 64 + ntp * 16 + lm;
        float ga = do_ln ? gamma[col] : 1.f;
        float be = do_ln ? beta[col] : 0.f;
#pragma unroll
        for (int mt = 0; mt < 4; ++mt)
#pragma unroll
            for (int r = 0; r < 4; ++r) {
                int rl = mt * 16 + quad * 4 + r;
                float v = xn[mt][ntp][r];
                float o = do_ln ? ((v - mu_s[rl]) * rs_s[rl] * ga + be) : v;
                h[(m0 + rl) * 256 + col] = (_Float16)o;
            }
    }
}

__global__ __launch_bounds__(256) void s5_k9_gemm_out(const _Float16* __restrict__ A,
                                                      const _Float16* __restrict__ Wt,
                                                      const float* __restrict__ bout,
                                                      float* __restrict__ out) {
    __shared__ _Float16 sA[128 * 64], sW[64 * 64];
    f32x4 acc[2][4];
    int m0 = blockIdx.x * 128;
    gemm_core<128, 64, 4, 1>(A, Wt, sA, sW, m0, 0, acc);
    int tid = threadIdx.x, wid = tid >> 6, lane = tid & 63, lm = lane & 15, quad = lane >> 4;
#pragma unroll
    for (int mt = 0; mt < 2; ++mt)
#pragma unroll
        for (int nt = 0; nt < 4; ++nt) {
            int col = nt * 16 + lm;
            float bv = bout[col];
#pragma unroll
            for (int r = 0; r < 4; ++r) {
                int row = m0 + wid * 32 + mt * 16 + quad * 4 + r;
                out[row * 64 + col] = acc[mt][nt][r] + bv;
            }
        }
}

// --------------------------- workspace layout (bytes) ----------------------
constexpr size_t OFF_X     = 0;                      // f32 L*256           33.5MB
constexpr size_t OFF_BU    = 33554432;               // f16 L*256 (alias xs2)
constexpr size_t OFF_XSH   = 50331648;               // f16 L*256 (alias g)
constexpr size_t OFF_H     = 67108864;               // f16 L*256
constexpr size_t OFF_WBU   = 83886080;               // f16 4*256*256
constexpr size_t OFF_WC    = OFF_WBU + 524288;
constexpr size_t OFF_WGLU  = OFF_WC + 524288;        // f16 4*512*256
constexpr size_t OFF_WOUT  = OFF_WGLU + 1048576;
constexpr size_t OFF_BGLU  = OFF_WOUT + 32768;       // f32 4*512
constexpr size_t OFF_AR    = OFF_BGLU + 8192;
constexpr size_t OFF_AI    = OFF_AR + 2048;
constexpr size_t OFF_CBR   = OFF_AI + 2048;
constexpr size_t OFF_CBI   = OFF_CBR + 2048;
constexpr size_t OFF_ATR   = OFF_CBI + 2048;
constexpr size_t OFF_ATI   = OFF_ATR + 2048;
constexpr size_t OFF_ALP   = OFF_ATI + 2048;
constexpr size_t OFF_RALP  = OFF_ALP + 2048;
constexpr size_t OFF_X0    = OFF_RALP + 2048;
constexpr size_t OFF_HROW  = OFF_X0 + 1024;
constexpr size_t OFF_HROW16= OFF_HROW + 1024;
constexpr size_t OFF_BUROW = OFF_HROW16 + 512;
constexpr size_t OFF_CARR  = OFF_BUROW + 1024;       // f32 256*128
constexpr size_t OFF_CARI  = OFF_CARR + 131072;
constexpr size_t OFF_CINR  = OFF_CARI + 131072;
constexpr size_t OFF_CINI  = OFF_CINR + 131072;

extern "C" void kernel_launch(void* const* d_in, const int* in_sizes, int n_in,
                              void* d_out, int out_size, void* d_ws, size_t ws_size,
                              hipStream_t stream) {
    (void)in_sizes; (void)n_in; (void)out_size; (void)ws_size;
    const float* latent    = (const float*)d_in[0];
    const float* W_expand  = (const float*)d_in[1];
    const float* b_expand  = (const float*)d_in[2];
    const float* norm_s    = (const float*)d_in[3];
    const float* norm_b    = (const float*)d_in[4];
    const float* Lre       = (const float*)d_in[5];
    const float* Lim       = (const float*)d_in[6];
    const float* Bre       = (const float*)d_in[7];
    const float* Bim       = (const float*)d_in[8];
    const float* Cre       = (const float*)d_in[9];
    const float* Cim       = (const float*)d_in[10];
    const float* Dv        = (const float*)d_in[11];
    const float* lstep     = (const float*)d_in[12];
    const float* W1        = (const float*)d_in[13];
    const float* b1        = (const float*)d_in[14];
    const float* W2        = (const float*)d_in[15];
    const float* b2        = (const float*)d_in[16];
    const float* Wout      = (const float*)d_in[17];
    const float* bout      = (const float*)d_in[18];

    char* ws = (char*)d_ws;
    float*    x     = (float*)(ws + OFF_X);
    _Float16* Bu16  = (_Float16*)(ws + OFF_BU);
    _Float16* xs2   = (_Float16*)(ws + OFF_BU);    // alias: Bu dead after k4
    _Float16* xsh   = (_Float16*)(ws + OFF_XSH);
    _Float16* gbuf  = (_Float16*)(ws + OFF_XSH);   // alias: xsh dead after k6
    _Float16* hbuf  = (_Float16*)(ws + OFF_H);
    _Float16* Wbu   = (_Float16*)(ws + OFF_WBU);
    _Float16* Wc    = (_Float16*)(ws + OFF_WC);
    _Float16* Wglu  = (_Float16*)(ws + OFF_WGLU);
    _Float16* WoutT = (_Float16*)(ws + OFF_WOUT);
    float* bglu  = (float*)(ws + OFF_BGLU);
    float* aR    = (float*)(ws + OFF_AR);
    float* aI    = (float*)(ws + OFF_AI);
    float* cbR   = (float*)(ws + OFF_CBR);
    float* cbI   = (float*)(ws + OFF_CBI);
    float* aTR   = (float*)(ws + OFF_ATR);
    float* aTI   = (float*)(ws + OFF_ATI);
    float* alp   = (float*)(ws + OFF_ALP);
    float* ralp  = (float*)(ws + OFF_RALP);
    float* x0    = (float*)(ws + OFF_X0);
    float* hrow  = (float*)(ws + OFF_HROW);
    _Float16* hrow16 = (_Float16*)(ws + OFF_HROW16);
    float* burow = (float*)(ws + OFF_BUROW);
    float* carR  = (float*)(ws + OFF_CARR);
    float* carI  = (float*)(ws + OFF_CARI);
    float* cinR  = (float*)(ws + OFF_CINR);
    float* cinI  = (float*)(ws + OFF_CINI);

    s5_k0a<<<1, 512, 0, stream>>>(Lre, Lim, lstep, aR, aI, cbR, cbI, aTR, aTI, alp, ralp);
    s5_k0b<<<256, 256, 0, stream>>>(Bre, Bim, Cre, Cim, W1, W2, b1, b2, Wout,
                                    cbR, cbI, alp, ralp, Wbu, Wc, Wglu, WoutT, bglu);
    s5_k0c<<<1, 256, 0, stream>>>(latent, W_expand, b_expand, norm_s, norm_b, x0, hrow, hrow16);
    s5_k0e<<<2, 128, 0, stream>>>(hrow, Wbu, burow);
    s5_k1_fill<<<8192, 256, 0, stream>>>(x0, x);

    for (int l = 0; l < 4; ++l) {
        if (l > 0)
            s5_k3_gemm_bu<<<dim3(256, 2), 256, 0, stream>>>(hbuf, Wbu + l * 65536, Bu16);
        s5_k4_scan<<<NCH, 128, 0, stream>>>(Bu16, burow, (l == 0) ? 1 : 0,
                                            aR + l * 128, aI + l * 128, xsh, carR, carI);
        s5_k5_carry<<<1, 128, 0, stream>>>(carR, carI, aTR + l * 128, aTI + l * 128, cinR, cinI);
        s5_k6_apply<<<NCH, 128, 0, stream>>>(xsh, cinR, cinI, aR + l * 128, aI + l * 128, xs2);
        s5_k7_gemm_c<<<512, 256, 0, stream>>>(xs2, Wc + l * 65536,
                                              (l == 0) ? hrow16 : hbuf, (l == 0) ? 0 : 256,
                                              Dv + l * 256, norm_s + l * 256, norm_b + l * 256, gbuf);
        int nl = (l + 1) & 3;
        s5_k8_glu_ln<<<512, 256, 0, stream>>>(gbuf, Wglu + l * 131072, bglu + l * 512,
                                              x, hbuf, norm_s + nl * 256, norm_b + nl * 256,
                                              (l < 3) ? 1 : 0, (l < 3) ? 1 : 0);
    }
    s5_k9_gemm_out<<<256, 256, 0, stream>>>(hbuf, WoutT, bout, (float*)d_out);
}